// Round 8
// baseline (1344.253 us; speedup 1.0000x reference)
//
#include <hip/hip_runtime.h>
#include <cmath>

#define DEV __device__ __forceinline__

static DEV float leakyf(float x){ return x >= 0.0f ? x : 0.2f*x; }

typedef float v2f __attribute__((ext_vector_type(2)));

// ---------------- Dopri5 tableau ----------------
constexpr float cA21 = (float)(1.0/5.0);
constexpr float cA31 = (float)(3.0/40.0),  cA32 = (float)(9.0/40.0);
constexpr float cA41 = (float)(44.0/45.0), cA42 = (float)(-56.0/15.0), cA43 = (float)(32.0/9.0);
constexpr float cA51 = (float)(19372.0/6561.0), cA52 = (float)(-25360.0/2187.0);
constexpr float cA53 = (float)(64448.0/6561.0), cA54 = (float)(-212.0/729.0);
constexpr float cA61 = (float)(9017.0/3168.0),  cA62 = (float)(-355.0/33.0);
constexpr float cA63 = (float)(46732.0/5247.0), cA64 = (float)(49.0/176.0);
constexpr float cA65 = (float)(-5103.0/18656.0);
constexpr float cB1 = (float)(35.0/384.0),  cB3 = (float)(500.0/1113.0), cB4 = (float)(125.0/192.0);
constexpr float cB5 = (float)(-2187.0/6784.0), cB6 = (float)(11.0/84.0);
constexpr float cE1 = (float)(71.0/57600.0), cE3 = (float)(-71.0/16695.0), cE4 = (float)(71.0/1920.0);
constexpr float cE5 = (float)(-17253.0/339200.0), cE6 = (float)(22.0/525.0), cE7 = (float)(-1.0/40.0);

// ---------------- workspace layout (float indices into d_ws) ----------------
// Barrier = verified R3/R5 shape: per-BLOCK value slots, 496 one-shot rows (1 MB).
// Dead ends: R4 per-wave slots (10x poll FETCH); R6 bpermute feval (+100us);
// R8 DPP all-gather feval (+76us); R9 fused-asm feval (+18us — compiler already
// emitted no intermediate wait; R7 feval is locally optimal).
#define WS_BTEN   2304                   // 4096 floats  : B(p) 16x16x16 (leaky applied)
#define WS_ZS     6400                   // 32*2048*16 = 1048576 floats : z trajectory
#define WS_SLOTSF (6400 + 1048576)       // 496 rows * 256 u64 = 253952 floats

// ---- DPP helpers (ctrl must be an ICE -> template param) -----------------------
template<int CTRL>
static DEV float dpp_add(float v){
    int x = __builtin_amdgcn_update_dpp(0, __float_as_int(v), CTRL, 0xf, 0xf, true);
    return v + __int_as_float(x);
}
// VALU-only frozen-tree wave reduction (verified R7: == butterfly bitwise)
static DEV float wave_sum_frozen(float w){
    w = dpp_add<0xB1>(w);    // quad_perm [1,0,3,2]  : xor1 partner
    w = dpp_add<0x4E>(w);    // quad_perm [2,3,0,1]  : xor2 partner
    w = dpp_add<0x141>(w);   // row_half_mirror (l^7): xor4 partner (quads equal)
    w = dpp_add<0x140>(w);   // row_mirror     (l^15): xor8 partner (8-grps equal)
    int b = __float_as_int(w);
    float q0 = __int_as_float(__builtin_amdgcn_readlane(b, 0));
    float q1 = __int_as_float(__builtin_amdgcn_readlane(b, 16));
    float q2 = __int_as_float(__builtin_amdgcn_readlane(b, 32));
    float q3 = __int_as_float(__builtin_amdgcn_readlane(b, 48));
    return (q0 + q1) + (q2 + q3);        // == butterfly xor16,xor32 association
}

// ================= K2: B-net (redundant per block) + Bten — 256 blocks ==============
// R10: k_smallnets(B-half) + k_hb3 folded in. Each block recomputes sb1/sb2/hb3 in
// LDS (identical j-ascending chains -> bit-exact), then its 16 Bten outputs with the
// FROZEN 16x128 part-split + halving tree. Kills the 1-block kernel (255 CUs idle)
// and two launches.
__global__ void __launch_bounds__(256) k_bten(
    const float* __restrict__ p,
    const float* __restrict__ Wb1, const float* __restrict__ bb1,
    const float* __restrict__ Wb2, const float* __restrict__ bb2,
    const float* __restrict__ Wb3, const float* __restrict__ bb3,
    const float* __restrict__ Wb4, const float* __restrict__ bb4,
    float* __restrict__ wsf)
{
    __shared__ float sp[4], sb1[16], sb2[64];
    __shared__ float hb3[2048];
    __shared__ float red[256];
    float* Bten = wsf + WS_BTEN;
    int tid = threadIdx.x;

    if (tid < 4) sp[tid] = p[tid];
    __syncthreads();
    if (tid < 16) {
        float c = bb1[tid];
        for (int j = 0; j < 4; ++j) c = fmaf(sp[j], Wb1[j*16+tid], c);
        sb1[tid] = leakyf(c);                       // chain == old k_smallnets
    }
    __syncthreads();
    if (tid < 64) {
        float c = bb2[tid];
        for (int j = 0; j < 16; ++j) c = fmaf(sb1[j], Wb2[j*64+tid], c);
        sb2[tid] = leakyf(c);                       // chain == old k_smallnets
    }
    __syncthreads();
    for (int q = 0; q < 8; ++q) {                   // hb3: chain == old k_hb3
        int o = q*256 + tid;
        float c = bb3[o];
        for (int j = 0; j < 64; ++j) c = fmaf(sb2[j], Wb3[(size_t)j*2048 + o], c);
        hb3[o] = leakyf(c);
    }
    __syncthreads();

    int ol = tid & 15, part = tid >> 4;             // 16 outputs/block, 16 hh-parts of 128
    int o = blockIdx.x * 16 + ol;
    float a = 0.0f;
    for (int q = 0; q < 128; ++q) {
        int hh = part*128 + q;
        a = fmaf(hb3[hh], Wb4[(size_t)hh*4096 + o], a);
    }
    red[part*16 + ol] = a;
    __syncthreads();
    for (int s = 8; s >= 1; s >>= 1) {
        if (part < s) red[part*16+ol] += red[(part+s)*16+ol];
        __syncthreads();
    }
    if (tid < 16) {
        float v = red[tid] + bb4[blockIdx.x*16 + tid];
        Bten[blockIdx.x*16 + tid] = leakyf(v);
    }
}

// ================= K4: A-net + encoder (fused) + Dopri5 solver =======================
// 256 blocks x 256 threads, co-resident on 256 CUs. FROZEN arithmetic (bit-exact draw):
// 2 threads per (b,i), 8+8 k-split, pk-fma pairs, frozen balanced-tree reductions,
// per-BLOCK value slots (R3/R5 barrier), R7 feval (LDS round-trip + DPP combine).
// R10: A-net computed block-locally in phase 0a (identical chains -> bit-exact Amat);
// encoder phase 0b unchanged. Kills k_smallnets.
__global__ void __launch_bounds__(256) k_solver(
    const float* __restrict__ tstep,
    const float* __restrict__ n0,
    const float* __restrict__ We1, const float* __restrict__ be1,
    const float* __restrict__ We2, const float* __restrict__ be2,
    const float* __restrict__ p,
    const float* __restrict__ Wa1, const float* __restrict__ ba1,
    const float* __restrict__ Wa2, const float* __restrict__ ba2,
    const float* __restrict__ Wa3, const float* __restrict__ ba3,
    float* __restrict__ wsf)
{
    __shared__ float hE[8][88];
    __shared__ float zE[8][16];
    __shared__ float zL[8][16];
    __shared__ float sp[4], sa1[16], sa2[128], sAmat[256];
    __shared__ float redA[2][4], redB[2][4];
    float* Bten = wsf + WS_BTEN;
    float* zs   = wsf + WS_ZS;
    unsigned long long* slots = (unsigned long long*)(wsf + WS_SLOTSF);

    const int tid = threadIdx.x, blk = blockIdx.x;
    const int e = tid >> 5, g = tid & 31;
    const int i = g >> 1, h = g & 1, h8 = h * 8;
    const int b = blk * 8 + e;

    // ---- phase 0a: A-net (identical chains to old k_smallnets A-half) ----
    {
        if (tid < 4) sp[tid] = p[tid];
        __syncthreads();
        if (tid < 16) {
            float a = ba1[tid];
            for (int j = 0; j < 4; ++j) a = fmaf(sp[j], Wa1[j*16+tid], a);
            sa1[tid] = leakyf(a);
        }
        __syncthreads();
        if (tid < 128) {
            float a = ba2[tid];
            for (int j = 0; j < 16; ++j) a = fmaf(sa1[j], Wa2[j*128+tid], a);
            sa2[tid] = leakyf(a);
        }
        __syncthreads();
        {
            float a = ba3[tid];
            for (int j = 0; j < 128; ++j) a = fmaf(sa2[j], Wa3[j*256+tid], a);
            sAmat[tid] = leakyf(a);
        }
        __syncthreads();
    }

    // ---- phase 0b: encoder (identical arithmetic to old k_encoder) ----
    {
        int r = tid >> 5, c = tid & 31;
        int row = blk * 8 + r;
        const float* nrow = n0 + (size_t)row * 466;
        int c2 = (c + 64 < 86) ? (c + 64) : 85;  // clamp (discarded if invalid)
        float a0 = 0.f, a1 = 0.f, a2 = 0.f;
        for (int n = 0; n < 466; ++n) {
            float nv = nrow[n];
            a0 = fmaf(nv, We1[n*86 + c], a0);
            a1 = fmaf(nv, We1[n*86 + c + 32], a1);
            a2 = fmaf(nv, We1[n*86 + c2], a2);
        }
        hE[r][c]      = leakyf(a0 + be1[c]);
        hE[r][c + 32] = leakyf(a1 + be1[c + 32]);
        if (c < 22) hE[r][c + 64] = leakyf(a2 + be1[c + 64]);
        __syncthreads();
        if (tid < 128) {
            int r2 = tid >> 4, ii = tid & 15;
            float a = be2[ii];
            #pragma unroll
            for (int hh = 0; hh < 86; ++hh) a = fmaf(hE[r2][hh], We2[hh*16 + ii], a);
            zE[r2][ii] = a;                                   // NO leaky on z0
            zs[((size_t)(blk*8 + r2)) * 16 + ii] = a;         // slab 0 for decoder
        }
        __syncthreads();
    }

    // --- per-thread constants: B half-slice as jj-pairs (v2f), A row pairs ---
    v2f Bl2[64], aR2[8];
    #pragma unroll
    for (int p2 = 0; p2 < 8; ++p2) {
        int jA = (h8 + 2*p2)     & 15;
        int jB = (h8 + 2*p2 + 1) & 15;
        v2f ap; ap.x = (h == 0) ? sAmat[i*16 + 2*p2] : 0.0f;
        ap.y = (h == 0) ? sAmat[i*16 + 2*p2 + 1] : 0.0f;
        aR2[p2] = ap;
        const float4* bpA = (const float4*)(Bten + i*256 + jA*16 + h8);
        const float4* bpB = (const float4*)(Bten + i*256 + jB*16 + h8);
        float4 a0 = bpA[0], a1 = bpA[1], b0 = bpB[0], b1 = bpB[1];
        v2f q;
        q.x=a0.x; q.y=b0.x; Bl2[p2*8+0]=q;  q.x=a0.y; q.y=b0.y; Bl2[p2*8+1]=q;
        q.x=a0.z; q.y=b0.z; Bl2[p2*8+2]=q;  q.x=a0.w; q.y=b0.w; Bl2[p2*8+3]=q;
        q.x=a1.x; q.y=b1.x; Bl2[p2*8+4]=q;  q.x=a1.y; q.y=b1.y; Bl2[p2*8+5]=q;
        q.x=a1.z; q.y=b1.z; Bl2[p2*8+6]=q;  q.x=a1.w; q.y=b1.w; Bl2[p2*8+7]=q;
    }

    float y = zE[e][i];

    auto feval = [&](float zi) -> float {
        zL[e][i] = zi;                                // both h lanes write same value
        const float4* zp = (const float4*)(&zL[e][0]);
        int q0 = h8 >> 2;                             // rotated read: zz[m]=z[(h8+m)&15]
        float4 r0 = zp[q0], r1 = zp[(q0+1)&3], r2 = zp[(q0+2)&3], r3 = zp[(q0+3)&3];
        float zz[16] = { r0.x,r0.y,r0.z,r0.w, r1.x,r1.y,r1.z,r1.w,
                         r2.x,r2.y,r2.z,r2.w, r3.x,r3.y,r3.z,r3.w };
        v2f zb[8];
        #pragma unroll
        for (int kk = 0; kk < 8; ++kk) { v2f t; t.x = zz[kk]; t.y = zz[kk]; zb[kk] = t; }
        v2f t2[8];
        #pragma unroll
        for (int p2 = 0; p2 < 8; ++p2) t2[p2] = aR2[p2];
        #pragma unroll
        for (int p2 = 0; p2 < 8; ++p2) {
            #pragma unroll
            for (int kk = 0; kk < 8; ++kk)
                asm("v_pk_fma_f32 %0, %1, %2, %0" : "+v"(t2[p2]) : "v"(Bl2[p2*8+kk]), "v"(zb[kk]));
        }
        float acc = 0.0f;
        #pragma unroll
        for (int p2 = 0; p2 < 8; ++p2) {
            acc = fmaf(zz[2*p2],     t2[p2].x, acc);
            acc = fmaf(zz[2*p2 + 1], t2[p2].y, acc);
        }
        // combine the two k-halves: xor1 partner via DPP (value == __shfl_xor(acc,1))
        acc = dpp_add<0xB1>(acc);
        return acc;
    };

    float dt = (tstep[1] - tstep[0]) * 0.3f;
    float k1 = feval(y), k2, k3, k4, k5, k6, k7;
    int stepIdx = 0;

    for (int iv = 0; iv < 31; ++iv) {
        float t  = tstep[iv];
        float t1 = tstep[iv + 1];
        for (int it = 0; it < 16; ++it) {
            if (t >= t1 - 1e-10f) break;              // 'done' iterations are exact no-ops
            float dtc = fminf(dt, t1 - t);

            float z2 = fmaf(dtc, cA21*k1, y);                                         k2 = feval(z2);
            float z3 = fmaf(dtc, fmaf(cA32,k2, cA31*k1), y);                          k3 = feval(z3);
            float z4 = fmaf(dtc, fmaf(cA43,k3, fmaf(cA42,k2, cA41*k1)), y);           k4 = feval(z4);
            float z5 = fmaf(dtc, fmaf(cA54,k4, fmaf(cA53,k3, fmaf(cA52,k2, cA51*k1))), y);
            k5 = feval(z5);
            float z6 = fmaf(dtc, fmaf(cA65,k5, fmaf(cA64,k4, fmaf(cA63,k3, fmaf(cA62,k2, cA61*k1)))), y);
            k6 = feval(z6);
            float y5 = fmaf(dtc, fmaf(cB6,k6, fmaf(cB5,k5, fmaf(cB4,k4, fmaf(cB3,k3, cB1*k1)))), y);
            k7 = feval(y5);
            float err = dtc * fmaf(cE7,k7, fmaf(cE6,k6, fmaf(cE5,k5, fmaf(cE4,k4, fmaf(cE3,k3, cE1*k1)))));

            float ay = fabsf(y), a5 = fabsf(y5);
            float mx = (ay > a5) ? ay : a5;           // NaN-propagating max (matches jnp)
            float tol = fmaf(1e-5f, mx, 1e-20f);
            float r = err / tol;
            float r2 = r * r;

            const int par = stepIdx & 1;

            // ---- block partial sum (h-duplicated; divide by 65536 at the end) ----
            float w = wave_sum_frozen(r2);
            if ((tid & 63) == 0) redA[par][tid >> 6] = w;
            __syncthreads();
            float bsum = ((redA[par][0] + redA[par][1]) + redA[par][2]) + redA[par][3];

            // ---- decentralized grid barrier: value-carrying 64-bit slots ----
            unsigned long long* rowp = slots + (size_t)stepIdx * 256;
            if (tid == 0) {
                unsigned long long pv = (1ull << 32) | (unsigned long long)__float_as_uint(bsum);
                __hip_atomic_store(&rowp[blk], pv, __ATOMIC_RELAXED, __HIP_MEMORY_SCOPE_AGENT);
            }
            unsigned long long v = __hip_atomic_load(&rowp[tid], __ATOMIC_RELAXED, __HIP_MEMORY_SCOPE_AGENT);
            if ((unsigned)(v >> 32) != 1u) {
                for (;;) {
                    unsigned long long va = __hip_atomic_load(&rowp[tid], __ATOMIC_RELAXED, __HIP_MEMORY_SCOPE_AGENT);
                    unsigned long long vb = __hip_atomic_load(&rowp[tid], __ATOMIC_RELAXED, __HIP_MEMORY_SCOPE_AGENT);
                    if ((unsigned)(va >> 32) == 1u) { v = va; break; }
                    if ((unsigned)(vb >> 32) == 1u) { v = vb; break; }
                }
            }
            float ps = wave_sum_frozen(__uint_as_float((unsigned)v));
            if ((tid & 63) == 0) redB[par][tid >> 6] = ps;
            __syncthreads();
            float gsum = ((redB[par][0] + redB[par][1]) + redB[par][2]) + redB[par][3];
            ++stepIdx;

            float en = sqrtf(gsum * (1.0f / 65536.0f));   // /65536: h-dup (x2) * mean (/32768)

            if (!(en == en)) {
                // NaN controller state is a fixed point of the reference: y frozen forever.
                if (h == 0) {
                    for (int s = iv + 1; s < 32; ++s)
                        zs[((size_t)s * 2048 + b) * 16 + i] = y;
                }
                return;
            }
            if (en <= 1.0f) { t = t + dtc; y = y5; k1 = k7; }   // accept (+FSAL)
            float fac = 0.9f * powf(fmaxf(en, 1e-12f), -0.2f);
            fac = fminf(fmaxf(fac, 0.2f), 10.0f);
            dt = dt * fac;
        }
        if (h == 0) zs[((size_t)(iv + 1) * 2048 + b) * 16 + i] = y;
    }
}

// ================= K5: decoder  out = leaky(zs@Wd1+bd1)@Wd2 + bd2 ====================
// 16 rows/block, TRANSPOSED hidden tile hT[86][16]: phase 2 reads the 16 row-values
// per hh as 4 broadcast ds_read_b128. Per-output fmaf chain order identical to the
// reference mapping (hh ascending). Verified win in R4.
__global__ void __launch_bounds__(256) k_decoder(
    const float* __restrict__ zs,
    const float* __restrict__ Wd1, const float* __restrict__ bd1,
    const float* __restrict__ Wd2, const float* __restrict__ bd2,
    float* __restrict__ out)
{
    __shared__ __align__(16) float hT[86][16];
    int tid = threadIdx.x;
    size_t rowbase = (size_t)blockIdx.x * 16;

    for (int v = tid; v < 86*16; v += 256) {
        int hh = v >> 4, r = v & 15;                  // 16 lanes share hh -> broadcast Wd1
        const float4* z4 = (const float4*)(zs + (rowbase + r) * 16);
        float4 za = z4[0], zb = z4[1], zc = z4[2], zd = z4[3];
        float a = bd1[hh];
        a = fmaf(za.x, Wd1[ 0*86 + hh], a);  a = fmaf(za.y, Wd1[ 1*86 + hh], a);
        a = fmaf(za.z, Wd1[ 2*86 + hh], a);  a = fmaf(za.w, Wd1[ 3*86 + hh], a);
        a = fmaf(zb.x, Wd1[ 4*86 + hh], a);  a = fmaf(zb.y, Wd1[ 5*86 + hh], a);
        a = fmaf(zb.z, Wd1[ 6*86 + hh], a);  a = fmaf(zb.w, Wd1[ 7*86 + hh], a);
        a = fmaf(zc.x, Wd1[ 8*86 + hh], a);  a = fmaf(zc.y, Wd1[ 9*86 + hh], a);
        a = fmaf(zc.z, Wd1[10*86 + hh], a);  a = fmaf(zc.w, Wd1[11*86 + hh], a);
        a = fmaf(zd.x, Wd1[12*86 + hh], a);  a = fmaf(zd.y, Wd1[13*86 + hh], a);
        a = fmaf(zd.z, Wd1[14*86 + hh], a);  a = fmaf(zd.w, Wd1[15*86 + hh], a);
        hT[hh][r] = leakyf(a);
    }
    __syncthreads();

    for (int c = tid; c < 466; c += 256) {
        float acc[16];
        #pragma unroll
        for (int r = 0; r < 16; ++r) acc[r] = bd2[c];
        for (int hh = 0; hh < 86; ++hh) {
            float w = Wd2[hh*466 + c];
            const float4* hp = (const float4*)(&hT[hh][0]);
            float4 h0 = hp[0], h1 = hp[1], h2 = hp[2], h3 = hp[3];
            acc[ 0] = fmaf(h0.x, w, acc[ 0]);  acc[ 1] = fmaf(h0.y, w, acc[ 1]);
            acc[ 2] = fmaf(h0.z, w, acc[ 2]);  acc[ 3] = fmaf(h0.w, w, acc[ 3]);
            acc[ 4] = fmaf(h1.x, w, acc[ 4]);  acc[ 5] = fmaf(h1.y, w, acc[ 5]);
            acc[ 6] = fmaf(h1.z, w, acc[ 6]);  acc[ 7] = fmaf(h1.w, w, acc[ 7]);
            acc[ 8] = fmaf(h2.x, w, acc[ 8]);  acc[ 9] = fmaf(h2.y, w, acc[ 9]);
            acc[10] = fmaf(h2.z, w, acc[10]);  acc[11] = fmaf(h2.w, w, acc[11]);
            acc[12] = fmaf(h3.x, w, acc[12]);  acc[13] = fmaf(h3.y, w, acc[13]);
            acc[14] = fmaf(h3.z, w, acc[14]);  acc[15] = fmaf(h3.w, w, acc[15]);
        }
        #pragma unroll
        for (int r = 0; r < 16; ++r) out[(rowbase + r) * 466 + c] = acc[r];
    }
}

// ====================================================================================
extern "C" void kernel_launch(void* const* d_in, const int* in_sizes, int n_in,
                              void* d_out, int out_size, void* d_ws, size_t ws_size,
                              hipStream_t stream)
{
    const float* n0   = (const float*)d_in[0];
    const float* p    = (const float*)d_in[1];
    const float* tstep= (const float*)d_in[2];
    const float* We1  = (const float*)d_in[3];  const float* be1 = (const float*)d_in[4];
    const float* We2  = (const float*)d_in[5];  const float* be2 = (const float*)d_in[6];
    const float* Wd1  = (const float*)d_in[7];  const float* bd1 = (const float*)d_in[8];
    const float* Wd2  = (const float*)d_in[9];  const float* bd2 = (const float*)d_in[10];
    const float* Wa1  = (const float*)d_in[11]; const float* ba1 = (const float*)d_in[12];
    const float* Wa2  = (const float*)d_in[13]; const float* ba2 = (const float*)d_in[14];
    const float* Wa3  = (const float*)d_in[15]; const float* ba3 = (const float*)d_in[16];
    const float* Wb1  = (const float*)d_in[17]; const float* bb1 = (const float*)d_in[18];
    const float* Wb2  = (const float*)d_in[19]; const float* bb2 = (const float*)d_in[20];
    const float* Wb3  = (const float*)d_in[21]; const float* bb3 = (const float*)d_in[22];
    const float* Wb4  = (const float*)d_in[23]; const float* bb4 = (const float*)d_in[24];
    float* out = (float*)d_out;
    float* wsf = (float*)d_ws;

    hipLaunchKernelGGL(k_bten, dim3(256), dim3(256), 0, stream,
                       p, Wb1, bb1, Wb2, bb2, Wb3, bb3, Wb4, bb4, wsf);

    // regular launch: 256 blocks <= 256 CUs -> co-resident; slot barrier is one-shot
    hipLaunchKernelGGL(k_solver, dim3(256), dim3(256), 0, stream,
                       tstep, n0, We1, be1, We2, be2,
                       p, Wa1, ba1, Wa2, ba2, Wa3, ba3, wsf);

    hipLaunchKernelGGL(k_decoder, dim3(4096), dim3(256), 0, stream,
                       wsf + WS_ZS, Wd1, bd1, Wd2, bd2, out);
}

// Round 9
// 1243.543 us; speedup vs baseline: 1.0810x; 1.0810x over previous
//
#include <hip/hip_runtime.h>
#include <cmath>

#define DEV __device__ __forceinline__

static DEV float leakyf(float x){ return x >= 0.0f ? x : 0.2f*x; }

typedef float v2f __attribute__((ext_vector_type(2)));

// ---------------- Dopri5 tableau ----------------
constexpr float cA21 = (float)(1.0/5.0);
constexpr float cA31 = (float)(3.0/40.0),  cA32 = (float)(9.0/40.0);
constexpr float cA41 = (float)(44.0/45.0), cA42 = (float)(-56.0/15.0), cA43 = (float)(32.0/9.0);
constexpr float cA51 = (float)(19372.0/6561.0), cA52 = (float)(-25360.0/2187.0);
constexpr float cA53 = (float)(64448.0/6561.0), cA54 = (float)(-212.0/729.0);
constexpr float cA61 = (float)(9017.0/3168.0),  cA62 = (float)(-355.0/33.0);
constexpr float cA63 = (float)(46732.0/5247.0), cA64 = (float)(49.0/176.0);
constexpr float cA65 = (float)(-5103.0/18656.0);
constexpr float cB1 = (float)(35.0/384.0),  cB3 = (float)(500.0/1113.0), cB4 = (float)(125.0/192.0);
constexpr float cB5 = (float)(-2187.0/6784.0), cB6 = (float)(11.0/84.0);
constexpr float cE1 = (float)(71.0/57600.0), cE3 = (float)(-71.0/16695.0), cE4 = (float)(71.0/1920.0);
constexpr float cE5 = (float)(-17253.0/339200.0), cE6 = (float)(22.0/525.0), cE7 = (float)(-1.0/40.0);

// ---------------- workspace layout (float indices into d_ws) ----------------
// Barrier = verified R3/R5 shape: per-BLOCK value slots, 496 one-shot rows (1 MB).
// Dead ends: R4 per-wave slots (10x poll FETCH); R6 bpermute feval (+100us);
// R8 DPP all-gather feval (+76us); R9 fused-asm feval (+18us); R10 per-block
// B-net inside k_bten (+100us on the pre-solver critical path).
#define WS_HB3    256                    // 2048 floats  : B-net hidden 3
#define WS_BTEN   2304                   // 4096 floats  : B(p) 16x16x16 (leaky applied)
#define WS_ZS     6400                   // 32*2048*16 = 1048576 floats : z trajectory
#define WS_SLOTSF (6400 + 1048576)       // 496 rows * 256 u64 = 253952 floats
#define WS_SB2    (WS_SLOTSF + 253952)   // 64 floats    : B-net hidden 2 (for k_hb3)

// ---- DPP helpers (ctrl must be an ICE -> template param) -----------------------
template<int CTRL>
static DEV float dpp_add(float v){
    int x = __builtin_amdgcn_update_dpp(0, __float_as_int(v), CTRL, 0xf, 0xf, true);
    return v + __int_as_float(x);
}
// VALU-only frozen-tree wave reduction (verified R7: == butterfly bitwise)
static DEV float wave_sum_frozen(float w){
    w = dpp_add<0xB1>(w);    // quad_perm [1,0,3,2]  : xor1 partner
    w = dpp_add<0x4E>(w);    // quad_perm [2,3,0,1]  : xor2 partner
    w = dpp_add<0x141>(w);   // row_half_mirror (l^7): xor4 partner (quads equal)
    w = dpp_add<0x140>(w);   // row_mirror     (l^15): xor8 partner (8-grps equal)
    int b = __float_as_int(w);
    float q0 = __int_as_float(__builtin_amdgcn_readlane(b, 0));
    float q1 = __int_as_float(__builtin_amdgcn_readlane(b, 16));
    float q2 = __int_as_float(__builtin_amdgcn_readlane(b, 32));
    float q3 = __int_as_float(__builtin_amdgcn_readlane(b, 48));
    return (q0 + q1) + (q2 + q3);        // == butterfly xor16,xor32 association
}

// ================= K1: B-net through sb2 — 1 block (A-net moved into solver) =========
__global__ void __launch_bounds__(256) k_smallnets(
    const float* __restrict__ p,
    const float* __restrict__ Wb1, const float* __restrict__ bb1,
    const float* __restrict__ Wb2, const float* __restrict__ bb2,
    float* __restrict__ wsf)
{
    __shared__ float sp[4], sb1[16];
    int tid = threadIdx.x;
    if (tid < 4) sp[tid] = p[tid];
    __syncthreads();
    if (tid < 16) {
        float c = bb1[tid];
        for (int j = 0; j < 4; ++j) c = fmaf(sp[j], Wb1[j*16+tid], c);
        sb1[tid] = leakyf(c);                 // chain order identical to R7
    }
    __syncthreads();
    if (tid < 64) {
        float c = bb2[tid];
        for (int j = 0; j < 16; ++j) c = fmaf(sb1[j], Wb2[j*64+tid], c);
        wsf[WS_SB2 + tid] = leakyf(c);        // chain order identical to R7
    }
}

// ================= K1b: hb3 = leaky(sb2 @ Wb3 + bb3) — 8 blocks ======================
__global__ void __launch_bounds__(256) k_hb3(
    const float* __restrict__ Wb3, const float* __restrict__ bb3, float* __restrict__ wsf)
{
    __shared__ float sb2[64];
    int tid = threadIdx.x;
    if (tid < 64) sb2[tid] = wsf[WS_SB2 + tid];
    __syncthreads();
    int o = blockIdx.x * 256 + tid;
    float c = bb3[o];
    for (int j = 0; j < 64; ++j) c = fmaf(sb2[j], Wb3[(size_t)j*2048 + o], c);
    wsf[WS_HB3 + o] = leakyf(c);             // same j-ascending chain as before
}

// ================= K2: Bten = leaky(hb3 @ Wb4 + bb4) — 256 blocks (R7 form) =========
__global__ void __launch_bounds__(256) k_bten(
    const float* __restrict__ Wb4, const float* __restrict__ bb4, float* __restrict__ wsf)
{
    __shared__ float red[256];
    const float* hb3 = wsf + WS_HB3;
    float* Bten = wsf + WS_BTEN;
    int tid = threadIdx.x;
    int ol = tid & 15, part = tid >> 4;          // 16 outputs/block, 16 hh-parts of 128
    int o = blockIdx.x * 16 + ol;
    float a = 0.0f;
    for (int q = 0; q < 128; ++q) {
        int hh = part*128 + q;
        a = fmaf(hb3[hh], Wb4[(size_t)hh*4096 + o], a);
    }
    red[part*16 + ol] = a;
    __syncthreads();
    for (int s = 8; s >= 1; s >>= 1) {
        if (part < s) red[part*16+ol] += red[(part+s)*16+ol];
        __syncthreads();
    }
    if (tid < 16) {
        float v = red[tid] + bb4[blockIdx.x*16 + tid];
        Bten[blockIdx.x*16 + tid] = leakyf(v);
    }
}

// ================= K4: A-net + encoder (fused) + Dopri5 solver =======================
// 256 blocks x 256 threads, co-resident on 256 CUs. FROZEN arithmetic (bit-exact draw):
// 2 threads per (b,i), 8+8 k-split, pk-fma pairs, frozen balanced-tree reductions,
// per-BLOCK value slots (R3/R5 barrier), R7 feval (LDS round-trip + DPP combine),
// A-net phase 0a + encoder phase 0b (R10-validated: solver 996us).
__global__ void __launch_bounds__(256) k_solver(
    const float* __restrict__ tstep,
    const float* __restrict__ n0,
    const float* __restrict__ We1, const float* __restrict__ be1,
    const float* __restrict__ We2, const float* __restrict__ be2,
    const float* __restrict__ p,
    const float* __restrict__ Wa1, const float* __restrict__ ba1,
    const float* __restrict__ Wa2, const float* __restrict__ ba2,
    const float* __restrict__ Wa3, const float* __restrict__ ba3,
    float* __restrict__ wsf)
{
    __shared__ float hE[8][88];
    __shared__ float zE[8][16];
    __shared__ float zL[8][16];
    __shared__ float sp[4], sa1[16], sa2[128], sAmat[256];
    __shared__ float redA[2][4], redB[2][4];
    float* Bten = wsf + WS_BTEN;
    float* zs   = wsf + WS_ZS;
    unsigned long long* slots = (unsigned long long*)(wsf + WS_SLOTSF);

    const int tid = threadIdx.x, blk = blockIdx.x;
    const int e = tid >> 5, g = tid & 31;
    const int i = g >> 1, h = g & 1, h8 = h * 8;
    const int b = blk * 8 + e;

    // ---- phase 0a: A-net (identical chains to old k_smallnets A-half) ----
    {
        if (tid < 4) sp[tid] = p[tid];
        __syncthreads();
        if (tid < 16) {
            float a = ba1[tid];
            for (int j = 0; j < 4; ++j) a = fmaf(sp[j], Wa1[j*16+tid], a);
            sa1[tid] = leakyf(a);
        }
        __syncthreads();
        if (tid < 128) {
            float a = ba2[tid];
            for (int j = 0; j < 16; ++j) a = fmaf(sa1[j], Wa2[j*128+tid], a);
            sa2[tid] = leakyf(a);
        }
        __syncthreads();
        {
            float a = ba3[tid];
            for (int j = 0; j < 128; ++j) a = fmaf(sa2[j], Wa3[j*256+tid], a);
            sAmat[tid] = leakyf(a);
        }
        __syncthreads();
    }

    // ---- phase 0b: encoder (identical arithmetic to old k_encoder) ----
    {
        int r = tid >> 5, c = tid & 31;
        int row = blk * 8 + r;
        const float* nrow = n0 + (size_t)row * 466;
        int c2 = (c + 64 < 86) ? (c + 64) : 85;  // clamp (discarded if invalid)
        float a0 = 0.f, a1 = 0.f, a2 = 0.f;
        for (int n = 0; n < 466; ++n) {
            float nv = nrow[n];
            a0 = fmaf(nv, We1[n*86 + c], a0);
            a1 = fmaf(nv, We1[n*86 + c + 32], a1);
            a2 = fmaf(nv, We1[n*86 + c2], a2);
        }
        hE[r][c]      = leakyf(a0 + be1[c]);
        hE[r][c + 32] = leakyf(a1 + be1[c + 32]);
        if (c < 22) hE[r][c + 64] = leakyf(a2 + be1[c + 64]);
        __syncthreads();
        if (tid < 128) {
            int r2 = tid >> 4, ii = tid & 15;
            float a = be2[ii];
            #pragma unroll
            for (int hh = 0; hh < 86; ++hh) a = fmaf(hE[r2][hh], We2[hh*16 + ii], a);
            zE[r2][ii] = a;                                   // NO leaky on z0
            zs[((size_t)(blk*8 + r2)) * 16 + ii] = a;         // slab 0 for decoder
        }
        __syncthreads();
    }

    // --- per-thread constants: B half-slice as jj-pairs (v2f), A row pairs ---
    v2f Bl2[64], aR2[8];
    #pragma unroll
    for (int p2 = 0; p2 < 8; ++p2) {
        int jA = (h8 + 2*p2)     & 15;
        int jB = (h8 + 2*p2 + 1) & 15;
        v2f ap; ap.x = (h == 0) ? sAmat[i*16 + 2*p2] : 0.0f;
        ap.y = (h == 0) ? sAmat[i*16 + 2*p2 + 1] : 0.0f;
        aR2[p2] = ap;
        const float4* bpA = (const float4*)(Bten + i*256 + jA*16 + h8);
        const float4* bpB = (const float4*)(Bten + i*256 + jB*16 + h8);
        float4 a0 = bpA[0], a1 = bpA[1], b0 = bpB[0], b1 = bpB[1];
        v2f q;
        q.x=a0.x; q.y=b0.x; Bl2[p2*8+0]=q;  q.x=a0.y; q.y=b0.y; Bl2[p2*8+1]=q;
        q.x=a0.z; q.y=b0.z; Bl2[p2*8+2]=q;  q.x=a0.w; q.y=b0.w; Bl2[p2*8+3]=q;
        q.x=a1.x; q.y=b1.x; Bl2[p2*8+4]=q;  q.x=a1.y; q.y=b1.y; Bl2[p2*8+5]=q;
        q.x=a1.z; q.y=b1.z; Bl2[p2*8+6]=q;  q.x=a1.w; q.y=b1.w; Bl2[p2*8+7]=q;
    }

    float y = zE[e][i];

    auto feval = [&](float zi) -> float {
        zL[e][i] = zi;                                // both h lanes write same value
        const float4* zp = (const float4*)(&zL[e][0]);
        int q0 = h8 >> 2;                             // rotated read: zz[m]=z[(h8+m)&15]
        float4 r0 = zp[q0], r1 = zp[(q0+1)&3], r2 = zp[(q0+2)&3], r3 = zp[(q0+3)&3];
        float zz[16] = { r0.x,r0.y,r0.z,r0.w, r1.x,r1.y,r1.z,r1.w,
                         r2.x,r2.y,r2.z,r2.w, r3.x,r3.y,r3.z,r3.w };
        v2f zb[8];
        #pragma unroll
        for (int kk = 0; kk < 8; ++kk) { v2f t; t.x = zz[kk]; t.y = zz[kk]; zb[kk] = t; }
        v2f t2[8];
        #pragma unroll
        for (int p2 = 0; p2 < 8; ++p2) t2[p2] = aR2[p2];
        #pragma unroll
        for (int p2 = 0; p2 < 8; ++p2) {
            #pragma unroll
            for (int kk = 0; kk < 8; ++kk)
                asm("v_pk_fma_f32 %0, %1, %2, %0" : "+v"(t2[p2]) : "v"(Bl2[p2*8+kk]), "v"(zb[kk]));
        }
        float acc = 0.0f;
        #pragma unroll
        for (int p2 = 0; p2 < 8; ++p2) {
            acc = fmaf(zz[2*p2],     t2[p2].x, acc);
            acc = fmaf(zz[2*p2 + 1], t2[p2].y, acc);
        }
        // combine the two k-halves: xor1 partner via DPP (value == __shfl_xor(acc,1))
        acc = dpp_add<0xB1>(acc);
        return acc;
    };

    float dt = (tstep[1] - tstep[0]) * 0.3f;
    float k1 = feval(y), k2, k3, k4, k5, k6, k7;
    int stepIdx = 0;

    for (int iv = 0; iv < 31; ++iv) {
        float t  = tstep[iv];
        float t1 = tstep[iv + 1];
        for (int it = 0; it < 16; ++it) {
            if (t >= t1 - 1e-10f) break;              // 'done' iterations are exact no-ops
            float dtc = fminf(dt, t1 - t);

            float z2 = fmaf(dtc, cA21*k1, y);                                         k2 = feval(z2);
            float z3 = fmaf(dtc, fmaf(cA32,k2, cA31*k1), y);                          k3 = feval(z3);
            float z4 = fmaf(dtc, fmaf(cA43,k3, fmaf(cA42,k2, cA41*k1)), y);           k4 = feval(z4);
            float z5 = fmaf(dtc, fmaf(cA54,k4, fmaf(cA53,k3, fmaf(cA52,k2, cA51*k1))), y);
            k5 = feval(z5);
            float z6 = fmaf(dtc, fmaf(cA65,k5, fmaf(cA64,k4, fmaf(cA63,k3, fmaf(cA62,k2, cA61*k1)))), y);
            k6 = feval(z6);
            float y5 = fmaf(dtc, fmaf(cB6,k6, fmaf(cB5,k5, fmaf(cB4,k4, fmaf(cB3,k3, cB1*k1)))), y);
            k7 = feval(y5);
            float err = dtc * fmaf(cE7,k7, fmaf(cE6,k6, fmaf(cE5,k5, fmaf(cE4,k4, fmaf(cE3,k3, cE1*k1)))));

            float ay = fabsf(y), a5 = fabsf(y5);
            float mx = (ay > a5) ? ay : a5;           // NaN-propagating max (matches jnp)
            float tol = fmaf(1e-5f, mx, 1e-20f);
            float r = err / tol;
            float r2 = r * r;

            const int par = stepIdx & 1;

            // ---- block partial sum (h-duplicated; divide by 65536 at the end) ----
            float w = wave_sum_frozen(r2);
            if ((tid & 63) == 0) redA[par][tid >> 6] = w;
            __syncthreads();
            float bsum = ((redA[par][0] + redA[par][1]) + redA[par][2]) + redA[par][3];

            // ---- decentralized grid barrier: value-carrying 64-bit slots ----
            unsigned long long* rowp = slots + (size_t)stepIdx * 256;
            if (tid == 0) {
                unsigned long long pv = (1ull << 32) | (unsigned long long)__float_as_uint(bsum);
                __hip_atomic_store(&rowp[blk], pv, __ATOMIC_RELAXED, __HIP_MEMORY_SCOPE_AGENT);
            }
            unsigned long long v = __hip_atomic_load(&rowp[tid], __ATOMIC_RELAXED, __HIP_MEMORY_SCOPE_AGENT);
            if ((unsigned)(v >> 32) != 1u) {
                for (;;) {
                    unsigned long long va = __hip_atomic_load(&rowp[tid], __ATOMIC_RELAXED, __HIP_MEMORY_SCOPE_AGENT);
                    unsigned long long vb = __hip_atomic_load(&rowp[tid], __ATOMIC_RELAXED, __HIP_MEMORY_SCOPE_AGENT);
                    if ((unsigned)(va >> 32) == 1u) { v = va; break; }
                    if ((unsigned)(vb >> 32) == 1u) { v = vb; break; }
                }
            }
            float ps = wave_sum_frozen(__uint_as_float((unsigned)v));
            if ((tid & 63) == 0) redB[par][tid >> 6] = ps;
            __syncthreads();
            float gsum = ((redB[par][0] + redB[par][1]) + redB[par][2]) + redB[par][3];
            ++stepIdx;

            float en = sqrtf(gsum * (1.0f / 65536.0f));   // /65536: h-dup (x2) * mean (/32768)

            if (!(en == en)) {
                // NaN controller state is a fixed point of the reference: y frozen forever.
                if (h == 0) {
                    for (int s = iv + 1; s < 32; ++s)
                        zs[((size_t)s * 2048 + b) * 16 + i] = y;
                }
                return;
            }
            if (en <= 1.0f) { t = t + dtc; y = y5; k1 = k7; }   // accept (+FSAL)
            float fac = 0.9f * powf(fmaxf(en, 1e-12f), -0.2f);
            fac = fminf(fmaxf(fac, 0.2f), 10.0f);
            dt = dt * fac;
        }
        if (h == 0) zs[((size_t)(iv + 1) * 2048 + b) * 16 + i] = y;
    }
}

// ================= K5: decoder  out = leaky(zs@Wd1+bd1)@Wd2 + bd2 ====================
// 16 rows/block, TRANSPOSED hidden tile hT[86][16]: phase 2 reads the 16 row-values
// per hh as 4 broadcast ds_read_b128. Per-output fmaf chain order identical to the
// reference mapping (hh ascending). Verified win in R4.
__global__ void __launch_bounds__(256) k_decoder(
    const float* __restrict__ zs,
    const float* __restrict__ Wd1, const float* __restrict__ bd1,
    const float* __restrict__ Wd2, const float* __restrict__ bd2,
    float* __restrict__ out)
{
    __shared__ __align__(16) float hT[86][16];
    int tid = threadIdx.x;
    size_t rowbase = (size_t)blockIdx.x * 16;

    for (int v = tid; v < 86*16; v += 256) {
        int hh = v >> 4, r = v & 15;                  // 16 lanes share hh -> broadcast Wd1
        const float4* z4 = (const float4*)(zs + (rowbase + r) * 16);
        float4 za = z4[0], zb = z4[1], zc = z4[2], zd = z4[3];
        float a = bd1[hh];
        a = fmaf(za.x, Wd1[ 0*86 + hh], a);  a = fmaf(za.y, Wd1[ 1*86 + hh], a);
        a = fmaf(za.z, Wd1[ 2*86 + hh], a);  a = fmaf(za.w, Wd1[ 3*86 + hh], a);
        a = fmaf(zb.x, Wd1[ 4*86 + hh], a);  a = fmaf(zb.y, Wd1[ 5*86 + hh], a);
        a = fmaf(zb.z, Wd1[ 6*86 + hh], a);  a = fmaf(zb.w, Wd1[ 7*86 + hh], a);
        a = fmaf(zc.x, Wd1[ 8*86 + hh], a);  a = fmaf(zc.y, Wd1[ 9*86 + hh], a);
        a = fmaf(zc.z, Wd1[10*86 + hh], a);  a = fmaf(zc.w, Wd1[11*86 + hh], a);
        a = fmaf(zd.x, Wd1[12*86 + hh], a);  a = fmaf(zd.y, Wd1[13*86 + hh], a);
        a = fmaf(zd.z, Wd1[14*86 + hh], a);  a = fmaf(zd.w, Wd1[15*86 + hh], a);
        hT[hh][r] = leakyf(a);
    }
    __syncthreads();

    for (int c = tid; c < 466; c += 256) {
        float acc[16];
        #pragma unroll
        for (int r = 0; r < 16; ++r) acc[r] = bd2[c];
        for (int hh = 0; hh < 86; ++hh) {
            float w = Wd2[hh*466 + c];
            const float4* hp = (const float4*)(&hT[hh][0]);
            float4 h0 = hp[0], h1 = hp[1], h2 = hp[2], h3 = hp[3];
            acc[ 0] = fmaf(h0.x, w, acc[ 0]);  acc[ 1] = fmaf(h0.y, w, acc[ 1]);
            acc[ 2] = fmaf(h0.z, w, acc[ 2]);  acc[ 3] = fmaf(h0.w, w, acc[ 3]);
            acc[ 4] = fmaf(h1.x, w, acc[ 4]);  acc[ 5] = fmaf(h1.y, w, acc[ 5]);
            acc[ 6] = fmaf(h1.z, w, acc[ 6]);  acc[ 7] = fmaf(h1.w, w, acc[ 7]);
            acc[ 8] = fmaf(h2.x, w, acc[ 8]);  acc[ 9] = fmaf(h2.y, w, acc[ 9]);
            acc[10] = fmaf(h2.z, w, acc[10]);  acc[11] = fmaf(h2.w, w, acc[11]);
            acc[12] = fmaf(h3.x, w, acc[12]);  acc[13] = fmaf(h3.y, w, acc[13]);
            acc[14] = fmaf(h3.z, w, acc[14]);  acc[15] = fmaf(h3.w, w, acc[15]);
        }
        #pragma unroll
        for (int r = 0; r < 16; ++r) out[(rowbase + r) * 466 + c] = acc[r];
    }
}

// ====================================================================================
extern "C" void kernel_launch(void* const* d_in, const int* in_sizes, int n_in,
                              void* d_out, int out_size, void* d_ws, size_t ws_size,
                              hipStream_t stream)
{
    const float* n0   = (const float*)d_in[0];
    const float* p    = (const float*)d_in[1];
    const float* tstep= (const float*)d_in[2];
    const float* We1  = (const float*)d_in[3];  const float* be1 = (const float*)d_in[4];
    const float* We2  = (const float*)d_in[5];  const float* be2 = (const float*)d_in[6];
    const float* Wd1  = (const float*)d_in[7];  const float* bd1 = (const float*)d_in[8];
    const float* Wd2  = (const float*)d_in[9];  const float* bd2 = (const float*)d_in[10];
    const float* Wa1  = (const float*)d_in[11]; const float* ba1 = (const float*)d_in[12];
    const float* Wa2  = (const float*)d_in[13]; const float* ba2 = (const float*)d_in[14];
    const float* Wa3  = (const float*)d_in[15]; const float* ba3 = (const float*)d_in[16];
    const float* Wb1  = (const float*)d_in[17]; const float* bb1 = (const float*)d_in[18];
    const float* Wb2  = (const float*)d_in[19]; const float* bb2 = (const float*)d_in[20];
    const float* Wb3  = (const float*)d_in[21]; const float* bb3 = (const float*)d_in[22];
    const float* Wb4  = (const float*)d_in[23]; const float* bb4 = (const float*)d_in[24];
    float* out = (float*)d_out;
    float* wsf = (float*)d_ws;

    hipLaunchKernelGGL(k_smallnets, dim3(1), dim3(256), 0, stream,
                       p, Wb1, bb1, Wb2, bb2, wsf);
    hipLaunchKernelGGL(k_hb3, dim3(8), dim3(256), 0, stream, Wb3, bb3, wsf);
    hipLaunchKernelGGL(k_bten, dim3(256), dim3(256), 0, stream, Wb4, bb4, wsf);

    // regular launch: 256 blocks <= 256 CUs -> co-resident; slot barrier is one-shot
    hipLaunchKernelGGL(k_solver, dim3(256), dim3(256), 0, stream,
                       tstep, n0, We1, be1, We2, be2,
                       p, Wa1, ba1, Wa2, ba2, Wa3, ba3, wsf);

    hipLaunchKernelGGL(k_decoder, dim3(4096), dim3(256), 0, stream,
                       wsf + WS_ZS, Wd1, bd1, Wd2, bd2, out);
}